// Round 7
// baseline (69.164 us; speedup 1.0000x reference)
//
#include <hip/hip_runtime.h>
#include <hip/hip_fp16.h>

// Joint bilateral filter, K=5, zero padding, f32 LDS tile + software-pipelined rows.
// t: (2,3,720,1280) f32 guide; v: (2,2,720,1280) f32 flow; out: (2,2,720,1280) f32
// coeff = max(0.875 - 50*sum_c (t_c - ts_c)^2, 0); out = sum(vs*coeff)/sum(coeff)
//
// Round-5 structure (proven: 0 bank conflicts, absmax 0.0078) with ONE change:
// the 5-row compute loop is an explicit double-buffered pipeline so row r+1's
// ds_read_b128 batch overlaps row r's ~440-cycle tap compute. launch_bounds
// (256,4) caps VGPR at 128 (4 waves/SIMD) to prevent the round-3 blowup.

constexpr int H_ = 720;
constexpr int W_ = 1280;
constexpr int HW = H_ * W_;
constexpr float COEF0 = 0.875f;  // 1 - |NEG_SS_DIV|
constexpr float SIDIV = 50.0f;   // 1/(2*0.1^2)

constexpr int TC = 136;          // staged cols (gx0-4 .. gx0+131), 16B-aligned
constexpr int TR = 12;           // staged rows (gy0-2 .. gy0+9)
constexpr int NCHUNK = 5 * TR * (TC / 4);   // 2040 float4 chunks; LDS byte = 16*i

// load one staged row's 12-wide windows (5 channels) into a register buffer
#define LOADW(BUF, ROWR)                                                        \
    do {                                                                        \
        const int lr_ = ty + (ROWR);                                            \
        _Pragma("unroll") for (int ch_ = 0; ch_ < 5; ++ch_)                     \
            _Pragma("unroll") for (int s_ = 0; s_ < 3; ++s_)                    \
                *(float4*)&BUF[ch_][4 * s_] =                                   \
                    *(const float4*)&lds[ch_][lr_][lc + 4 * s_];                \
    } while (0)

// accumulate 5x4 taps from a window buffer (only k in [2,9] is live)
#define COMPW(BUF)                                                              \
    do {                                                                        \
        _Pragma("unroll") for (int dx_ = 0; dx_ < 5; ++dx_)                     \
            _Pragma("unroll") for (int j_ = 0; j_ < 4; ++j_) {                  \
                const int k_ = dx_ + j_ + 2;                                    \
                const float d0_ = c0f[j_] - BUF[0][k_];                         \
                const float d1_ = c1f[j_] - BUF[1][k_];                         \
                const float d2_ = c2f[j_] - BUF[2][k_];                         \
                float diff_ = d0_ * d0_;                                        \
                diff_ = fmaf(d1_, d1_, diff_);                                  \
                diff_ = fmaf(d2_, d2_, diff_);                                  \
                const float c_ = fmaxf(fmaf(diff_, -SIDIV, COEF0), 0.f);        \
                num0[j_] = fmaf(BUF[3][k_], c_, num0[j_]);                      \
                num1[j_] = fmaf(BUF[4][k_], c_, num1[j_]);                      \
                den[j_] += c_;                                                  \
            }                                                                   \
    } while (0)

__global__ __launch_bounds__(256, 4)
void jbf_pipe(const float* __restrict__ t, const float* __restrict__ v,
              float* __restrict__ out) {
    __shared__ float lds[5][TR][TC];        // 32,640 B; flat float4 idx == chunk idx

    const int bx = blockIdx.x % 10;         // 10 x-tiles of 128
    const int by = (blockIdx.x / 10) % 90;  // 90 y-tiles of 8
    const int n  = blockIdx.x / 900;        // 2 images
    const int gx0 = bx * 128;
    const int gy0 = by * 8;

    const float* tn = t + (size_t)n * 3 * HW;
    const float* vn = v + (size_t)n * 2 * HW;
    float*       on = out + (size_t)n * 2 * HW;

    const int tid = threadIdx.x;

    // ---------------- stage tile into LDS ----------------
#pragma unroll
    for (int it = 0; it < 8; ++it) {
        const int i = tid + it * 256;
        if (i < NCHUNK) {
            const int c4 = i % 34;           // col chunk (4 floats)
            const int rr = (i / 34) % TR;    // staged row
            const int ch = i / (34 * TR);    // 0..2 = t, 3..4 = v
            const int gy = gy0 - 2 + rr;
            const int gx = gx0 - 4 + 4 * c4; // multiple of 4 -> chunk all-in or all-out
            float4 val = make_float4(0.f, 0.f, 0.f, 0.f);
            if ((unsigned)gy < (unsigned)H_ && (unsigned)gx < (unsigned)(W_ - 3)) {
                const float* src = (ch < 3) ? (tn + (size_t)ch * HW)
                                            : (vn + (size_t)(ch - 3) * HW);
                val = *(const float4*)(src + gy * W_ + gx);
            }
            ((float4*)lds)[i] = val;         // byte 16*i == &lds[ch][rr][4*c4]
        }
    }
    __syncthreads();

    // ---------------- compute 4 px from LDS, pipelined rows ----------------
    const int tx = tid & 31;                 // x-group within tile
    const int ty = tid >> 5;                 // output row within tile
    const int lc = 4 * tx;                   // window base col (k=0 <-> col lc)

    // centers: staged row ty+2, cols lc+4..lc+7
    float c0f[4], c1f[4], c2f[4];
    *(float4*)c0f = *(const float4*)&lds[0][ty + 2][lc + 4];
    *(float4*)c1f = *(const float4*)&lds[1][ty + 2][lc + 4];
    *(float4*)c2f = *(const float4*)&lds[2][ty + 2][lc + 4];

    float num0[4] = {0.f, 0.f, 0.f, 0.f};
    float num1[4] = {0.f, 0.f, 0.f, 0.f};
    float den[4]  = {0.f, 0.f, 0.f, 0.f};

    float A[5][12], B[5][12];
    LOADW(A, 0);                 // row 0 windows
    LOADW(B, 1);                 // row 1 in flight while row 0 computes
    COMPW(A);
    LOADW(A, 2);
    COMPW(B);
    LOADW(B, 3);
    COMPW(A);
    LOADW(A, 4);
    COMPW(B);
    COMPW(A);

    float4 o0, o1;
    float* o0a = (float*)&o0;
    float* o1a = (float*)&o1;
#pragma unroll
    for (int j = 0; j < 4; ++j) {
        const float rcp = 1.f / den[j];
        // mimic the reference's fp16 round-trip
        o0a[j] = __half2float(__float2half(num0[j] * rcp));
        o1a[j] = __half2float(__float2half(num1[j] * rcp));
    }
    const int ctr = (gy0 + ty) * W_ + gx0 + 4 * tx;
    *(float4*)(on + ctr) = o0;
    *(float4*)(on + HW + ctr) = o1;
}

extern "C" void kernel_launch(void* const* d_in, const int* in_sizes, int n_in,
                              void* d_out, int out_size, void* d_ws, size_t ws_size,
                              hipStream_t stream) {
    const float* t = (const float*)d_in[0];
    const float* v = (const float*)d_in[1];
    float* out = (float*)d_out;

    // 10 x-tiles * 90 y-tiles * 2 images = 1800 blocks of 256
    jbf_pipe<<<1800, 256, 0, stream>>>(t, v, out);
}

// Round 8
// 34.205 us; speedup vs baseline: 2.0220x; 2.0220x over previous
//
#include <hip/hip_runtime.h>
#include <hip/hip_fp16.h>

// Joint bilateral filter, K=5, zero padding, f32 LDS tile, 2 output rows/thread.
// t: (2,3,720,1280) f32 guide; v: (2,2,720,1280) f32 flow; out: (2,2,720,1280) f32
// coeff = max(0.875 - 50*sum_c (t_c - ts_c)^2, 0); out = sum(vs*coeff)/sum(coeff)
//
// Block = 256 threads -> output tile 128 cols x 16 rows; thread = 4px x 2 rows.
// The row pair shares its 6 staged window rows: DS reads drop 150->90 b128 per
// 8 px and each DS batch feeds 2x the VALU work (DS pipe no longer oversubscribed).
// Window arrays are declared fresh inside each scope and consumed immediately
// (round-5 idiom, proven to SROA; round-7's persistent double-buffers spilled).

constexpr int H_ = 720;
constexpr int W_ = 1280;
constexpr int HW = H_ * W_;
constexpr float COEF0 = 0.875f;  // 1 - |NEG_SS_DIV|
constexpr float SIDIV = 50.0f;   // 1/(2*0.1^2)

constexpr int TC = 136;          // staged cols (gx0-4 .. gx0+131), 16B-aligned
constexpr int TR = 20;           // staged rows (gy0-2 .. gy0+17)
constexpr int NCHUNK = 5 * TR * (TC / 4);   // 3400 float4 chunks; LDS byte = 16*i

// load one staged row's 12-wide windows (5 channels) into FRESH arrays in scope
#define LOADW(LR)                                                              \
    float w0[12], w1[12], w2[12], u0[12], u1[12];                              \
    _Pragma("unroll") for (int s_ = 0; s_ < 3; ++s_) {                         \
        *(float4*)(w0 + 4 * s_) = *(const float4*)&lds[0][LR][lc + 4 * s_];    \
        *(float4*)(w1 + 4 * s_) = *(const float4*)&lds[1][LR][lc + 4 * s_];    \
        *(float4*)(w2 + 4 * s_) = *(const float4*)&lds[2][LR][lc + 4 * s_];    \
        *(float4*)(u0 + 4 * s_) = *(const float4*)&lds[3][LR][lc + 4 * s_];    \
        *(float4*)(u1 + 4 * s_) = *(const float4*)&lds[4][LR][lc + 4 * s_];    \
    }

// accumulate 5x4 taps against centers C0/C1/C2 into N0/N1/DN (k in [2,9])
#define COMPW(C0, C1, C2, N0, N1, DN)                                          \
    _Pragma("unroll") for (int dx_ = 0; dx_ < 5; ++dx_)                        \
        _Pragma("unroll") for (int j_ = 0; j_ < 4; ++j_) {                     \
            const int k_ = dx_ + j_ + 2;                                       \
            const float d0_ = C0[j_] - w0[k_];                                 \
            const float d1_ = C1[j_] - w1[k_];                                 \
            const float d2_ = C2[j_] - w2[k_];                                 \
            float diff_ = d0_ * d0_;                                           \
            diff_ = fmaf(d1_, d1_, diff_);                                     \
            diff_ = fmaf(d2_, d2_, diff_);                                     \
            const float c_ = fmaxf(fmaf(diff_, -SIDIV, COEF0), 0.f);           \
            N0[j_] = fmaf(u0[k_], c_, N0[j_]);                                 \
            N1[j_] = fmaf(u1[k_], c_, N1[j_]);                                 \
            DN[j_] += c_;                                                      \
        }

__global__ __launch_bounds__(256, 2)
void jbf_dual(const float* __restrict__ t, const float* __restrict__ v,
              float* __restrict__ out) {
    __shared__ float lds[5][TR][TC];        // 54,400 B; flat float4 idx == chunk idx

    const int bx = blockIdx.x % 10;         // 10 x-tiles of 128
    const int by = (blockIdx.x / 10) % 45;  // 45 y-tiles of 16
    const int n  = blockIdx.x / 450;        // 2 images
    const int gx0 = bx * 128;
    const int gy0 = by * 16;

    const float* tn = t + (size_t)n * 3 * HW;
    const float* vn = v + (size_t)n * 2 * HW;
    float*       on = out + (size_t)n * 2 * HW;

    const int tid = threadIdx.x;

    // ---------------- stage tile into LDS ----------------
#pragma unroll
    for (int it = 0; it < 14; ++it) {
        const int i = tid + it * 256;
        if (i < NCHUNK) {
            const int c4 = i % 34;           // col chunk (4 floats)
            const int rr = (i / 34) % TR;    // staged row
            const int ch = i / (34 * TR);    // 0..2 = t, 3..4 = v
            const int gy = gy0 - 2 + rr;
            const int gx = gx0 - 4 + 4 * c4; // multiple of 4 -> chunk all-in or all-out
            float4 val = make_float4(0.f, 0.f, 0.f, 0.f);
            if ((unsigned)gy < (unsigned)H_ && (unsigned)gx < (unsigned)(W_ - 3)) {
                const float* src = (ch < 3) ? (tn + (size_t)ch * HW)
                                            : (vn + (size_t)(ch - 3) * HW);
                val = *(const float4*)(src + gy * W_ + gx);
            }
            ((float4*)lds)[i] = val;         // byte 16*i == &lds[ch][rr][4*c4]
        }
    }
    __syncthreads();

    // ---------------- compute 4 px x 2 rows from LDS ----------------
    const int tx = tid & 31;                 // x-group within tile
    const int ty = tid >> 5;                 // row-pair index 0..7
    const int lc = 4 * tx;                   // window base col (k=0 <-> col lc)
    const int r0 = 2 * ty;                   // first output row in tile

    // centers: row A = staged r0+2, row B = staged r0+3, cols lc+4..lc+7
    float cA0[4], cA1[4], cA2[4], cB0[4], cB1[4], cB2[4];
    *(float4*)cA0 = *(const float4*)&lds[0][r0 + 2][lc + 4];
    *(float4*)cA1 = *(const float4*)&lds[1][r0 + 2][lc + 4];
    *(float4*)cA2 = *(const float4*)&lds[2][r0 + 2][lc + 4];
    *(float4*)cB0 = *(const float4*)&lds[0][r0 + 3][lc + 4];
    *(float4*)cB1 = *(const float4*)&lds[1][r0 + 3][lc + 4];
    *(float4*)cB2 = *(const float4*)&lds[2][r0 + 3][lc + 4];

    float nA0[4] = {0, 0, 0, 0}, nA1[4] = {0, 0, 0, 0}, dA[4] = {0, 0, 0, 0};
    float nB0[4] = {0, 0, 0, 0}, nB1[4] = {0, 0, 0, 0}, dB[4] = {0, 0, 0, 0};

    {   // staged row r0+0: feeds row A only (dy=0)
        LOADW(r0)
        COMPW(cA0, cA1, cA2, nA0, nA1, dA)
    }
#pragma unroll 1
    for (int s = 1; s <= 4; ++s) {           // staged rows r0+1..r0+4: feed both
        const int lr = r0 + s;
        LOADW(lr)
        COMPW(cA0, cA1, cA2, nA0, nA1, dA)
        COMPW(cB0, cB1, cB2, nB0, nB1, dB)
    }
    {   // staged row r0+5: feeds row B only (dy=4)
        LOADW(r0 + 5)
        COMPW(cB0, cB1, cB2, nB0, nB1, dB)
    }

    // ---------------- epilogue ----------------
    float4 oA0, oA1, oB0, oB1;
    float* a0 = (float*)&oA0; float* a1 = (float*)&oA1;
    float* b0 = (float*)&oB0; float* b1 = (float*)&oB1;
#pragma unroll
    for (int j = 0; j < 4; ++j) {
        const float ra = 1.f / dA[j];
        const float rb = 1.f / dB[j];
        // mimic the reference's fp16 round-trip
        a0[j] = __half2float(__float2half(nA0[j] * ra));
        a1[j] = __half2float(__float2half(nA1[j] * ra));
        b0[j] = __half2float(__float2half(nB0[j] * rb));
        b1[j] = __half2float(__float2half(nB1[j] * rb));
    }
    const int ctrA = (gy0 + r0) * W_ + gx0 + 4 * tx;
    const int ctrB = ctrA + W_;
    *(float4*)(on + ctrA) = oA0;
    *(float4*)(on + HW + ctrA) = oA1;
    *(float4*)(on + ctrB) = oB0;
    *(float4*)(on + HW + ctrB) = oB1;
}

extern "C" void kernel_launch(void* const* d_in, const int* in_sizes, int n_in,
                              void* d_out, int out_size, void* d_ws, size_t ws_size,
                              hipStream_t stream) {
    const float* t = (const float*)d_in[0];
    const float* v = (const float*)d_in[1];
    float* out = (float*)d_out;

    // 10 x-tiles * 45 y-tiles * 2 images = 900 blocks of 256
    jbf_dual<<<900, 256, 0, stream>>>(t, v, out);
}